// Round 1
// baseline (2958.130 us; speedup 1.0000x reference)
//
#include <hip/hip_runtime.h>
#include <cstdint>

#define NODES   150000
#define DIM     64
#define EDGES   4000000
#define LABELS  8192
#define NUSERS  100000
#define NITEMS  50000

// ---------------- degree ----------------
__global__ void k_deg(const int* __restrict__ col, float* __restrict__ deg) {
    int e = blockIdx.x * blockDim.x + threadIdx.x;
    if (e < EDGES) atomicAdd(&deg[col[e]], 1.0f);
}

// deg -> dis = deg>0 ? deg^-0.5 : 0   (in place)
__global__ void k_dis(float* __restrict__ deg) {
    int n = blockIdx.x * blockDim.x + threadIdx.x;
    if (n < NODES) {
        float d = deg[n];
        deg[n] = d > 0.0f ? rsqrtf(d) : 0.0f;
    }
}

// per-edge norm = dis[row]*dis[col]
__global__ void k_enorm(const int* __restrict__ row, const int* __restrict__ col,
                        const float* __restrict__ dis, float* __restrict__ enorm) {
    int e = blockIdx.x * blockDim.x + threadIdx.x;
    if (e < EDGES) enorm[e] = dis[row[e]] * dis[col[e]];
}

// acc = alpha[0] * emb
__global__ void k_init_out(const float* __restrict__ emb, const float* __restrict__ alpha,
                           float* __restrict__ acc) {
    int i = blockIdx.x * blockDim.x + threadIdx.x;
    if (i < NODES * DIM) acc[i] = emb[i] * alpha[0];
}

// one 64-lane wave-group per edge, lane = dim
__global__ void k_scatter(const float* __restrict__ x, const int* __restrict__ row,
                          const int* __restrict__ col, const float* __restrict__ enorm,
                          float* __restrict__ xn) {
    int e    = (blockIdx.x << 2) + (threadIdx.x >> 6);
    int lane = threadIdx.x & 63;
    if (e >= EDGES) return;
    int   r  = row[e];
    int   c  = col[e];
    float nm = enorm[e];
    float v  = x[(r << 6) + lane] * nm;
    atomicAdd(&xn[(c << 6) + lane], v);
}

// acc += alpha[ai] * x
__global__ void k_axpy(float* __restrict__ acc, const float* __restrict__ x,
                       const float* __restrict__ alpha, int ai) {
    int i = blockIdx.x * blockDim.x + threadIdx.x;
    if (i < NODES * DIM) acc[i] += alpha[ai] * x[i];
}

// L2-normalize item rows in place: item = item / max(||item||,eps) * sf
__global__ void k_norm_items(float* __restrict__ acc, const float* __restrict__ sf) {
    int n    = NUSERS + (blockIdx.x << 2) + (threadIdx.x >> 6);
    int lane = threadIdx.x & 63;
    if (n >= NUSERS + NITEMS) return;
    float v  = acc[(n << 6) + lane];
    float ss = v * v;
    #pragma unroll
    for (int m = 1; m < 64; m <<= 1) ss += __shfl_xor(ss, m);
    float nrm = fmaxf(sqrtf(ss), 1e-12f);
    acc[(n << 6) + lane] = v * (sf[0] / nrm);
}

// rank[k] = dot(acc[src[k]], acc[dst[k]])
__global__ void k_rank(const float* __restrict__ acc, const int* __restrict__ eli,
                       float* __restrict__ rank) {
    int k    = (blockIdx.x << 2) + (threadIdx.x >> 6);
    int lane = threadIdx.x & 63;
    if (k >= LABELS) return;
    int s = eli[k];
    int d = eli[LABELS + k];
    float p = acc[(s << 6) + lane] * acc[(d << 6) + lane];
    #pragma unroll
    for (int m = 1; m < 64; m <<= 1) p += __shfl_xor(p, m);
    if (lane == 0) rank[k] = p;
}

// out[which][i][j] = rank[which*4096 + j] + beta[eli[LABELS + which*4096 + i]]
// 4 elems (float4) per thread; total 2*4096*4096 f32
__global__ void k_final(const float* __restrict__ rank, const float* __restrict__ beta,
                        const int* __restrict__ eli, float* __restrict__ out) {
    int t     = blockIdx.x * blockDim.x + threadIdx.x;   // [0, 2^23)
    int which = t >> 22;
    int tt    = t & ((1 << 22) - 1);
    int i     = tt >> 10;
    int j4    = (tt & 1023) << 2;
    int item  = eli[LABELS + (which << 12) + i];
    float b   = beta[item];
    const float* rk = rank + (which << 12);
    float4 r = *reinterpret_cast<const float4*>(rk + j4);
    float4 v = make_float4(r.x + b, r.y + b, r.z + b, r.w + b);
    *reinterpret_cast<float4*>(out + ((size_t)t << 2)) = v;
}

extern "C" void kernel_launch(void* const* d_in, const int* in_sizes, int n_in,
                              void* d_out, int out_size, void* d_ws, size_t ws_size,
                              hipStream_t stream) {
    const float* emb   = (const float*)d_in[0];
    const float* beta  = (const float*)d_in[1];
    const float* alpha = (const float*)d_in[2];
    const int*   eidx  = (const int*)d_in[3];
    const int*   eli   = (const int*)d_in[4];
    const float* sf    = (const float*)d_in[7];

    const int* row = eidx;
    const int* col = eidx + EDGES;

    float* ws    = (float*)d_ws;
    float* dis   = ws;                       // NODES (rounded to 151552)
    float* enorm = ws + 151552;              // EDGES
    float* A     = enorm + EDGES;            // NODES*DIM
    float* B     = A + NODES * DIM;          // NODES*DIM
    float* rank  = B + NODES * DIM;          // LABELS
    float* acc   = (float*)d_out;            // NODES*DIM accumulator in front of d_out

    const int NE_BLK  = (EDGES + 255) / 256;
    const int ND_BLK  = (NODES + 255) / 256;
    const int NV_BLK  = (NODES * DIM + 255) / 256;

    hipMemsetAsync(dis, 0, NODES * sizeof(float), stream);
    k_deg<<<NE_BLK, 256, 0, stream>>>(col, dis);
    k_dis<<<ND_BLK, 256, 0, stream>>>(dis);
    k_enorm<<<NE_BLK, 256, 0, stream>>>(row, col, dis, enorm);
    k_init_out<<<NV_BLK, 256, 0, stream>>>(emb, alpha, acc);

    // layer 1: emb -> A
    hipMemsetAsync(A, 0, (size_t)NODES * DIM * sizeof(float), stream);
    k_scatter<<<EDGES / 4, 256, 0, stream>>>(emb, row, col, enorm, A);
    k_axpy<<<NV_BLK, 256, 0, stream>>>(acc, A, alpha, 1);

    // layer 2: A -> B
    hipMemsetAsync(B, 0, (size_t)NODES * DIM * sizeof(float), stream);
    k_scatter<<<EDGES / 4, 256, 0, stream>>>(A, row, col, enorm, B);
    k_axpy<<<NV_BLK, 256, 0, stream>>>(acc, B, alpha, 2);

    // layer 3: B -> A
    hipMemsetAsync(A, 0, (size_t)NODES * DIM * sizeof(float), stream);
    k_scatter<<<EDGES / 4, 256, 0, stream>>>(B, row, col, enorm, A);
    k_axpy<<<NV_BLK, 256, 0, stream>>>(acc, A, alpha, 3);

    k_norm_items<<<NITEMS / 4, 256, 0, stream>>>(acc, sf);
    k_rank<<<LABELS / 4, 256, 0, stream>>>(acc, eli, rank);
    k_final<<<(1 << 23) / 256, 256, 0, stream>>>(rank, beta, eli, (float*)d_out);
}

// Round 2
// 1112.533 us; speedup vs baseline: 2.6589x; 2.6589x over previous
//
#include <hip/hip_runtime.h>
#include <cstdint>

#define NODES   150000
#define DIM     64
#define EDGES   4000000
#define LABELS  8192
#define NUSERS  100000
#define NITEMS  50000

#define SCAN_BLOCKS ((NODES + 255) / 256)   // 587

// integer degree of each destination node
__global__ void k_deg_i(const int* __restrict__ col, int* __restrict__ deg) {
    int e = blockIdx.x * blockDim.x + threadIdx.x;
    if (e < EDGES) atomicAdd(&deg[col[e]], 1);
}

// per-256-block inclusive scan of deg -> part, block totals -> bsum
__global__ void k_scan1(const int* __restrict__ deg, int* __restrict__ part,
                        int* __restrict__ bsum) {
    __shared__ int s[256];
    int i = blockIdx.x * 256 + threadIdx.x;
    int v = (i < NODES) ? deg[i] : 0;
    s[threadIdx.x] = v;
    __syncthreads();
    #pragma unroll
    for (int o = 1; o < 256; o <<= 1) {
        int t = (threadIdx.x >= o) ? s[threadIdx.x - o] : 0;
        __syncthreads();
        s[threadIdx.x] += t;
        __syncthreads();
    }
    if (i < NODES) part[i] = s[threadIdx.x];
    if (threadIdx.x == 255) bsum[blockIdx.x] = s[255];
}

// exclusive scan of the 587 block sums (tiny, serial)
__global__ void k_scan2(int* __restrict__ bsum) {
    if (threadIdx.x == 0) {
        int acc = 0;
        for (int b = 0; b < SCAN_BLOCKS; ++b) { int t = bsum[b]; bsum[b] = acc; acc += t; }
    }
}

// rowptr[i] = exclusive scan;  dis[i] = deg>0 ? deg^-0.5 : 0
__global__ void k_scan3(const int* __restrict__ part, const int* __restrict__ deg,
                        const int* __restrict__ bsum, int* __restrict__ rowptr,
                        float* __restrict__ dis) {
    int i = blockIdx.x * blockDim.x + threadIdx.x;
    if (i == NODES) rowptr[NODES] = EDGES;
    if (i < NODES) {
        rowptr[i] = part[i] - deg[i] + bsum[i >> 8];
        int d = deg[i];
        dis[i] = d > 0 ? rsqrtf((float)d) : 0.0f;
    }
}

// counting-sort edges by destination; fuse edge-norm computation
__global__ void k_fill(const int* __restrict__ row, const int* __restrict__ col,
                       const float* __restrict__ dis, const int* __restrict__ rowptr,
                       int* __restrict__ cursor, int* __restrict__ src_s,
                       float* __restrict__ nrm_s) {
    int e = blockIdx.x * blockDim.x + threadIdx.x;
    if (e >= EDGES) return;
    int c = col[e];
    int r = row[e];
    int pos = rowptr[c] + atomicAdd(&cursor[c], 1);
    src_s[pos] = r;
    nrm_s[pos] = dis[r] * dis[c];
}

// acc = alpha[0] * emb
__global__ void k_init_out(const float* __restrict__ emb, const float* __restrict__ alpha,
                           float* __restrict__ acc) {
    int i = blockIdx.x * blockDim.x + threadIdx.x;
    if (i < NODES * DIM) acc[i] = emb[i] * alpha[0];
}

// one wave per destination node: register segment-sum over its edges,
// write x_new and fused acc += alpha[ai]*x_new. No atomics, no pre-zeroing.
__global__ void k_gather(const float* __restrict__ x, const int* __restrict__ src_s,
                         const float* __restrict__ nrm_s, const int* __restrict__ rowptr,
                         float* __restrict__ xn, float* __restrict__ acc,
                         const float* __restrict__ alpha, int ai) {
    int n    = (blockIdx.x << 2) + (threadIdx.x >> 6);
    int lane = threadIdx.x & 63;
    if (n >= NODES) return;
    int jb = rowptr[n], je = rowptr[n + 1];
    float a0 = 0.0f, a1 = 0.0f;
    int j = jb;
    for (; j + 1 < je; j += 2) {
        int   s0 = src_s[j],  s1 = src_s[j + 1];
        float w0 = nrm_s[j],  w1 = nrm_s[j + 1];
        a0 += x[(s0 << 6) + lane] * w0;
        a1 += x[(s1 << 6) + lane] * w1;
    }
    if (j < je) a0 += x[(src_s[j] << 6) + lane] * nrm_s[j];
    float a = a0 + a1;
    int o = (n << 6) + lane;
    xn[o] = a;
    acc[o] += alpha[ai] * a;
}

// L2-normalize item rows in place
__global__ void k_norm_items(float* __restrict__ acc, const float* __restrict__ sf) {
    int n    = NUSERS + (blockIdx.x << 2) + (threadIdx.x >> 6);
    int lane = threadIdx.x & 63;
    if (n >= NUSERS + NITEMS) return;
    float v  = acc[(n << 6) + lane];
    float ss = v * v;
    #pragma unroll
    for (int m = 1; m < 64; m <<= 1) ss += __shfl_xor(ss, m);
    float nrm = fmaxf(sqrtf(ss), 1e-12f);
    acc[(n << 6) + lane] = v * (sf[0] / nrm);
}

// rank[k] = dot(acc[src[k]], acc[dst[k]])
__global__ void k_rank(const float* __restrict__ acc, const int* __restrict__ eli,
                       float* __restrict__ rank) {
    int k    = (blockIdx.x << 2) + (threadIdx.x >> 6);
    int lane = threadIdx.x & 63;
    if (k >= LABELS) return;
    int s = eli[k];
    int d = eli[LABELS + k];
    float p = acc[(s << 6) + lane] * acc[(d << 6) + lane];
    #pragma unroll
    for (int m = 1; m < 64; m <<= 1) p += __shfl_xor(p, m);
    if (lane == 0) rank[k] = p;
}

// out[which][i][j] = rank[which*4096 + j] + beta[eli[LABELS + which*4096 + i]]
__global__ void k_final(const float* __restrict__ rank, const float* __restrict__ beta,
                        const int* __restrict__ eli, float* __restrict__ out) {
    int t     = blockIdx.x * blockDim.x + threadIdx.x;   // [0, 2^23)
    int which = t >> 22;
    int tt    = t & ((1 << 22) - 1);
    int i     = tt >> 10;
    int j4    = (tt & 1023) << 2;
    int item  = eli[LABELS + (which << 12) + i];
    float b   = beta[item];
    const float* rk = rank + (which << 12);
    float4 r = *reinterpret_cast<const float4*>(rk + j4);
    float4 v = make_float4(r.x + b, r.y + b, r.z + b, r.w + b);
    *reinterpret_cast<float4*>(out + ((size_t)t << 2)) = v;
}

extern "C" void kernel_launch(void* const* d_in, const int* in_sizes, int n_in,
                              void* d_out, int out_size, void* d_ws, size_t ws_size,
                              hipStream_t stream) {
    const float* emb   = (const float*)d_in[0];
    const float* beta  = (const float*)d_in[1];
    const float* alpha = (const float*)d_in[2];
    const int*   eidx  = (const int*)d_in[3];
    const int*   eli   = (const int*)d_in[4];
    const float* sf    = (const float*)d_in[7];

    const int* row = eidx;
    const int* col = eidx + EDGES;

    // ---- workspace layout (4-byte units, regions 152064-aligned) ----
    char* ws = (char*)d_ws;
    int*   deg    = (int*)  (ws);
    int*   rowptr = (int*)  (ws + 152064 * 4);       // NODES+1
    int*   cursor = (int*)  (ws + 304128 * 4);
    float* dis    = (float*)(ws + 456192 * 4);
    int*   bsum   = (int*)  (ws + 608256 * 4);       // 587 (+pad)
    int*   part   = (int*)  (ws + 609280 * 4);       // NODES
    int*   src_s  = (int*)  (ws + 761344 * 4);       // EDGES
    float* nrm_s  = (float*)(ws + 4761344 * 4);      // EDGES
    float* rank   = (float*)(ws + 8761344 * 4);      // LABELS

    // layer ping-pong buffers live in the unused tail of d_out (33.5M floats)
    float* acc = (float*)d_out;                       // NODES*DIM = 9.6M
    float* A   = (float*)d_out + 10485760;
    float* B   = (float*)d_out + 20971520;

    const int NE_BLK = (EDGES + 255) / 256;
    const int NV_BLK = (NODES * DIM + 255) / 256;
    const int NN4    = (NODES + 3) / 4;

    // ---- CSR build ----
    hipMemsetAsync(deg, 0, NODES * sizeof(int), stream);
    hipMemsetAsync(cursor, 0, NODES * sizeof(int), stream);
    k_deg_i<<<NE_BLK, 256, 0, stream>>>(col, deg);
    k_scan1<<<SCAN_BLOCKS, 256, 0, stream>>>(deg, part, bsum);
    k_scan2<<<1, 64, 0, stream>>>(bsum);
    k_scan3<<<(NODES + 256) / 256, 256, 0, stream>>>(part, deg, bsum, rowptr, dis);
    k_fill<<<NE_BLK, 256, 0, stream>>>(row, col, dis, rowptr, cursor, src_s, nrm_s);

    // ---- propagation ----
    k_init_out<<<NV_BLK, 256, 0, stream>>>(emb, alpha, acc);
    k_gather<<<NN4, 256, 0, stream>>>(emb, src_s, nrm_s, rowptr, A, acc, alpha, 1);
    k_gather<<<NN4, 256, 0, stream>>>(A,   src_s, nrm_s, rowptr, B, acc, alpha, 2);
    k_gather<<<NN4, 256, 0, stream>>>(B,   src_s, nrm_s, rowptr, A, acc, alpha, 3);

    // ---- epilogue ----
    k_norm_items<<<NITEMS / 4, 256, 0, stream>>>(acc, sf);
    k_rank<<<LABELS / 4, 256, 0, stream>>>(acc, eli, rank);
    k_final<<<(1 << 23) / 256, 256, 0, stream>>>(rank, beta, eli, (float*)d_out);
}

// Round 3
// 1013.136 us; speedup vs baseline: 2.9198x; 1.0981x over previous
//
#include <hip/hip_runtime.h>
#include <cstdint>

#define NODES   150000
#define DIM     64
#define EDGES   4000000
#define LABELS  8192
#define NUSERS  100000
#define NITEMS  50000

#define SCAN_BLOCKS ((NODES + 255) / 256)   // 587

// integer degree of each destination node
__global__ void k_deg_i(const int* __restrict__ col, int* __restrict__ deg) {
    int e = blockIdx.x * blockDim.x + threadIdx.x;
    if (e < EDGES) atomicAdd(&deg[col[e]], 1);
}

// per-256-block inclusive scan of deg -> part, block totals -> bsum
__global__ void k_scan1(const int* __restrict__ deg, int* __restrict__ part,
                        int* __restrict__ bsum) {
    __shared__ int s[256];
    int i = blockIdx.x * 256 + threadIdx.x;
    int v = (i < NODES) ? deg[i] : 0;
    s[threadIdx.x] = v;
    __syncthreads();
    #pragma unroll
    for (int o = 1; o < 256; o <<= 1) {
        int t = (threadIdx.x >= o) ? s[threadIdx.x - o] : 0;
        __syncthreads();
        s[threadIdx.x] += t;
        __syncthreads();
    }
    if (i < NODES) part[i] = s[threadIdx.x];
    if (threadIdx.x == 255) bsum[blockIdx.x] = s[255];
}

// exclusive scan of the 587 block sums (tiny, serial)
__global__ void k_scan2(int* __restrict__ bsum) {
    if (threadIdx.x == 0) {
        int acc = 0;
        for (int b = 0; b < SCAN_BLOCKS; ++b) { int t = bsum[b]; bsum[b] = acc; acc += t; }
    }
}

// rowptr[i] = exclusive scan;  dis[i] = deg>0 ? deg^-0.5 : 0
__global__ void k_scan3(const int* __restrict__ part, const int* __restrict__ deg,
                        const int* __restrict__ bsum, int* __restrict__ rowptr,
                        float* __restrict__ dis) {
    int i = blockIdx.x * blockDim.x + threadIdx.x;
    if (i == NODES) rowptr[NODES] = EDGES;
    if (i < NODES) {
        rowptr[i] = part[i] - deg[i] + bsum[i >> 8];
        int d = deg[i];
        dis[i] = d > 0 ? rsqrtf((float)d) : 0.0f;
    }
}

// counting-sort edges by destination (src index only; norm is now implicit)
__global__ void k_fill(const int* __restrict__ row, const int* __restrict__ col,
                       const int* __restrict__ rowptr, int* __restrict__ cursor,
                       int* __restrict__ src_s) {
    int e = blockIdx.x * blockDim.x + threadIdx.x;
    if (e >= EDGES) return;
    int c = col[e];
    int pos = rowptr[c] + atomicAdd(&cursor[c], 1);
    src_s[pos] = row[e];
}

// acc = alpha[0]*emb ;  y0 = dis ⊙ emb
__global__ void k_prep(const float* __restrict__ emb, const float* __restrict__ alpha,
                       const float* __restrict__ dis, float* __restrict__ acc,
                       float* __restrict__ y0) {
    int i = blockIdx.x * blockDim.x + threadIdx.x;
    if (i < NODES * DIM) {
        float e = emb[i];
        acc[i] = e * alpha[0];
        y0[i]  = e * dis[i >> 6];
    }
}

// one wave per destination node:  s = Σ y[src];  x_new = dis[n]*s;
// acc += alpha[ai]*x_new;  y_next = dis[n]*x_new (skipped on last layer)
__global__ void k_gather(const float* __restrict__ y, const int* __restrict__ src_s,
                         const int* __restrict__ rowptr, const float* __restrict__ dis,
                         float* __restrict__ yn, float* __restrict__ acc,
                         const float* __restrict__ alpha, int ai, int write_yn) {
    int n    = (blockIdx.x << 2) + (threadIdx.x >> 6);
    int lane = threadIdx.x & 63;
    if (n >= NODES) return;
    int jb = rowptr[n], je = rowptr[n + 1];
    float a0 = 0.0f, a1 = 0.0f, a2 = 0.0f, a3 = 0.0f;
    int j = jb;
    for (; j + 3 < je; j += 4) {
        int s0 = src_s[j], s1 = src_s[j + 1], s2 = src_s[j + 2], s3 = src_s[j + 3];
        a0 += y[(s0 << 6) + lane];
        a1 += y[(s1 << 6) + lane];
        a2 += y[(s2 << 6) + lane];
        a3 += y[(s3 << 6) + lane];
    }
    for (; j < je; ++j) a0 += y[(src_s[j] << 6) + lane];
    float s    = (a0 + a1) + (a2 + a3);
    float d    = dis[n];
    float xnew = d * s;
    int   o    = (n << 6) + lane;
    if (write_yn) yn[o] = d * xnew;
    acc[o] += alpha[ai] * xnew;
}

// L2-normalize item rows in place
__global__ void k_norm_items(float* __restrict__ acc, const float* __restrict__ sf) {
    int n    = NUSERS + (blockIdx.x << 2) + (threadIdx.x >> 6);
    int lane = threadIdx.x & 63;
    if (n >= NUSERS + NITEMS) return;
    float v  = acc[(n << 6) + lane];
    float ss = v * v;
    #pragma unroll
    for (int m = 1; m < 64; m <<= 1) ss += __shfl_xor(ss, m);
    float nrm = fmaxf(sqrtf(ss), 1e-12f);
    acc[(n << 6) + lane] = v * (sf[0] / nrm);
}

// rank[k] = dot(acc[src[k]], acc[dst[k]])
__global__ void k_rank(const float* __restrict__ acc, const int* __restrict__ eli,
                       float* __restrict__ rank) {
    int k    = (blockIdx.x << 2) + (threadIdx.x >> 6);
    int lane = threadIdx.x & 63;
    if (k >= LABELS) return;
    int s = eli[k];
    int d = eli[LABELS + k];
    float p = acc[(s << 6) + lane] * acc[(d << 6) + lane];
    #pragma unroll
    for (int m = 1; m < 64; m <<= 1) p += __shfl_xor(p, m);
    if (lane == 0) rank[k] = p;
}

// out[which][i][j] = rank[which*4096 + j] + beta[eli[LABELS + which*4096 + i]]
__global__ void k_final(const float* __restrict__ rank, const float* __restrict__ beta,
                        const int* __restrict__ eli, float* __restrict__ out) {
    int t     = blockIdx.x * blockDim.x + threadIdx.x;   // [0, 2^23)
    int which = t >> 22;
    int tt    = t & ((1 << 22) - 1);
    int i     = tt >> 10;
    int j4    = (tt & 1023) << 2;
    int item  = eli[LABELS + (which << 12) + i];
    float b   = beta[item];
    const float* rk = rank + (which << 12);
    float4 r = *reinterpret_cast<const float4*>(rk + j4);
    float4 v = make_float4(r.x + b, r.y + b, r.z + b, r.w + b);
    *reinterpret_cast<float4*>(out + ((size_t)t << 2)) = v;
}

extern "C" void kernel_launch(void* const* d_in, const int* in_sizes, int n_in,
                              void* d_out, int out_size, void* d_ws, size_t ws_size,
                              hipStream_t stream) {
    const float* emb   = (const float*)d_in[0];
    const float* beta  = (const float*)d_in[1];
    const float* alpha = (const float*)d_in[2];
    const int*   eidx  = (const int*)d_in[3];
    const int*   eli   = (const int*)d_in[4];
    const float* sf    = (const float*)d_in[7];

    const int* row = eidx;
    const int* col = eidx + EDGES;

    // ---- workspace layout (regions in 4-byte units) ----
    char* ws = (char*)d_ws;
    int*   deg    = (int*)  (ws);
    int*   rowptr = (int*)  (ws + 152064 * 4);       // NODES+1
    int*   cursor = (int*)  (ws + 304128 * 4);
    float* dis    = (float*)(ws + 456192 * 4);
    int*   bsum   = (int*)  (ws + 608256 * 4);       // 587 (+pad)
    int*   part   = (int*)  (ws + 609280 * 4);       // NODES
    int*   src_s  = (int*)  (ws + 761344 * 4);       // EDGES
    float* rank   = (float*)(ws + 4761344 * 4);      // LABELS

    // layer ping-pong y buffers live in the unused tail of d_out (33.5M floats)
    float* acc = (float*)d_out;                       // NODES*DIM = 9.6M
    float* Y0  = (float*)d_out + 10485760;
    float* Y1  = (float*)d_out + 20971520;

    const int NE_BLK = (EDGES + 255) / 256;
    const int NV_BLK = (NODES * DIM + 255) / 256;
    const int NN4    = (NODES + 3) / 4;

    // ---- CSR build ----
    hipMemsetAsync(deg, 0, NODES * sizeof(int), stream);
    hipMemsetAsync(cursor, 0, NODES * sizeof(int), stream);
    k_deg_i<<<NE_BLK, 256, 0, stream>>>(col, deg);
    k_scan1<<<SCAN_BLOCKS, 256, 0, stream>>>(deg, part, bsum);
    k_scan2<<<1, 64, 0, stream>>>(bsum);
    k_scan3<<<(NODES + 256) / 256, 256, 0, stream>>>(part, deg, bsum, rowptr, dis);
    k_fill<<<NE_BLK, 256, 0, stream>>>(row, col, rowptr, cursor, src_s);

    // ---- propagation (y-space) ----
    k_prep<<<NV_BLK, 256, 0, stream>>>(emb, alpha, dis, acc, Y0);
    k_gather<<<NN4, 256, 0, stream>>>(Y0, src_s, rowptr, dis, Y1, acc, alpha, 1, 1);
    k_gather<<<NN4, 256, 0, stream>>>(Y1, src_s, rowptr, dis, Y0, acc, alpha, 2, 1);
    k_gather<<<NN4, 256, 0, stream>>>(Y0, src_s, rowptr, dis, Y1, acc, alpha, 3, 0);

    // ---- epilogue ----
    k_norm_items<<<NITEMS / 4, 256, 0, stream>>>(acc, sf);
    k_rank<<<LABELS / 4, 256, 0, stream>>>(acc, eli, rank);
    k_final<<<(1 << 23) / 256, 256, 0, stream>>>(rank, beta, eli, (float*)d_out);
}

// Round 4
// 652.165 us; speedup vs baseline: 4.5359x; 1.5535x over previous
//
#include <hip/hip_runtime.h>
#include <cstdint>

#define NODES   150000
#define DIM     64
#define EDGES   4000000
#define LABELS  8192
#define NUSERS  100000
#define NITEMS  50000

#define NB      586          // ceil(NODES/256) coarse buckets of 256 nodes
#define CAP     10240        // LDS entry capacity per bucket (mean 6827, +41 sigma)

// ---- pass A: coarse histogram (LDS-privatized) ----
__global__ void k_chist(const int* __restrict__ col, int* __restrict__ chist) {
    __shared__ int h[NB];
    for (int i = threadIdx.x; i < NB; i += 256) h[i] = 0;
    __syncthreads();
    int base = blockIdx.x * 4096;
    #pragma unroll
    for (int k = 0; k < 16; ++k) {
        int e = base + k * 256 + threadIdx.x;
        if (e < EDGES) atomicAdd(&h[col[e] >> 8], 1);
    }
    __syncthreads();
    for (int i = threadIdx.x; i < NB; i += 256) if (h[i]) atomicAdd(&chist[i], h[i]);
}

// ---- scan of 586 bucket counts (one wave, shuffle scan) ----
__global__ void k_scanB(const int* __restrict__ chist, int* __restrict__ cbase,
                        int* __restrict__ gcur) {
    int lane = threadIdx.x;
    int run = 0;
    for (int base = 0; base < NB; base += 64) {
        int idx = base + lane;
        int v = (idx < NB) ? chist[idx] : 0;
        int inc = v;
        #pragma unroll
        for (int o = 1; o < 64; o <<= 1) {
            int t = __shfl_up(inc, o);
            if (lane >= o) inc += t;
        }
        int ex = run + inc - v;
        if (idx < NB) { cbase[idx] = ex; gcur[idx] = ex; }
        run += __shfl(inc, 63);
    }
    if (lane == 0) cbase[NB] = EDGES;
}

// ---- pass B: coarse scatter into bucket-partitioned packed array ----
__global__ void k_cscatter(const int* __restrict__ row, const int* __restrict__ col,
                           int* __restrict__ gcur, unsigned* __restrict__ E) {
    __shared__ int lhist[NB];
    __shared__ int lbase[NB];
    for (int i = threadIdx.x; i < NB; i += 256) lhist[i] = 0;
    __syncthreads();
    int base = blockIdx.x * 8192;
    #pragma unroll
    for (int k = 0; k < 32; ++k) {
        int e = base + k * 256 + threadIdx.x;
        if (e < EDGES) atomicAdd(&lhist[col[e] >> 8], 1);
    }
    __syncthreads();
    for (int i = threadIdx.x; i < NB; i += 256) {
        int c = lhist[i];
        lbase[i] = c ? atomicAdd(&gcur[i], c) : 0;
        lhist[i] = 0;                       // reuse as local cursor
    }
    __syncthreads();
    #pragma unroll
    for (int k = 0; k < 32; ++k) {
        int e = base + k * 256 + threadIdx.x;
        if (e < EDGES) {
            int c = col[e];
            int b = c >> 8;
            int r = atomicAdd(&lhist[b], 1);
            E[lbase[b] + r] = ((unsigned)(c & 255) << 18) | (unsigned)row[e];
        }
    }
}

// ---- pass C: fine sort within one bucket per block; emits rowptr + dis too ----
__global__ void k_fsort(const unsigned* __restrict__ E, const int* __restrict__ cbase,
                        int* __restrict__ src_s, int* __restrict__ rowptr,
                        float* __restrict__ dis) {
    __shared__ unsigned ebuf[CAP];
    __shared__ int hist[256];
    __shared__ int curs[256];
    int b = blockIdx.x;
    int base = cbase[b], end = cbase[b + 1];
    int cnt = end - base;
    int t = threadIdx.x;
    hist[t] = 0;
    __syncthreads();
    for (int i = t; i < cnt; i += 256) {
        unsigned p = E[base + i];
        if (i < CAP) ebuf[i] = p;
        atomicAdd(&hist[p >> 18], 1);
    }
    __syncthreads();
    int v = hist[t];
    int inc = v;
    #pragma unroll
    for (int o = 1; o < 256; o <<= 1) {
        int tmp = (t >= o) ? hist[t - o] : 0;
        __syncthreads();
        hist[t] = inc = inc + tmp;
        __syncthreads();
    }
    int ex = inc - v;
    curs[t] = ex;
    int node = (b << 8) + t;
    if (node < NODES) {
        rowptr[node] = base + ex;
        dis[node] = v > 0 ? rsqrtf((float)v) : 0.0f;
    }
    if (b == NB - 1 && t == 0) rowptr[NODES] = EDGES;
    __syncthreads();
    for (int i = t; i < cnt; i += 256) {
        unsigned p = (i < CAP) ? ebuf[i] : E[base + i];
        int c = p >> 18;
        int r = atomicAdd(&curs[c], 1);
        src_s[base + r] = (int)(p & 0x3FFFFu);
    }
}

// ---- acc = alpha[0]*emb ;  y0 = dis ⊙ emb ----
__global__ void k_prep(const float* __restrict__ emb, const float* __restrict__ alpha,
                       const float* __restrict__ dis, float* __restrict__ acc,
                       float* __restrict__ y0) {
    int i = blockIdx.x * blockDim.x + threadIdx.x;
    if (i < NODES * DIM) {
        float e = emb[i];
        acc[i] = e * alpha[0];
        y0[i]  = e * dis[i >> 6];
    }
}

// ---- one wave per destination node: s = sum y[src]; fused acc update ----
__global__ void k_gather(const float* __restrict__ y, const int* __restrict__ src_s,
                         const int* __restrict__ rowptr, const float* __restrict__ dis,
                         float* __restrict__ yn, float* __restrict__ acc,
                         const float* __restrict__ alpha, int ai, int write_yn) {
    int n    = (blockIdx.x << 2) + (threadIdx.x >> 6);
    int lane = threadIdx.x & 63;
    if (n >= NODES) return;
    int jb = rowptr[n], je = rowptr[n + 1];
    float a0 = 0.0f, a1 = 0.0f, a2 = 0.0f, a3 = 0.0f;
    int j = jb;
    for (; j + 3 < je; j += 4) {
        int s0 = src_s[j], s1 = src_s[j + 1], s2 = src_s[j + 2], s3 = src_s[j + 3];
        a0 += y[(s0 << 6) + lane];
        a1 += y[(s1 << 6) + lane];
        a2 += y[(s2 << 6) + lane];
        a3 += y[(s3 << 6) + lane];
    }
    for (; j < je; ++j) a0 += y[(src_s[j] << 6) + lane];
    float s    = (a0 + a1) + (a2 + a3);
    float d    = dis[n];
    float xnew = d * s;
    int   o    = (n << 6) + lane;
    if (write_yn) yn[o] = d * xnew;
    acc[o] += alpha[ai] * xnew;
}

// ---- L2-normalize item rows in place ----
__global__ void k_norm_items(float* __restrict__ acc, const float* __restrict__ sf) {
    int n    = NUSERS + (blockIdx.x << 2) + (threadIdx.x >> 6);
    int lane = threadIdx.x & 63;
    if (n >= NUSERS + NITEMS) return;
    float v  = acc[(n << 6) + lane];
    float ss = v * v;
    #pragma unroll
    for (int m = 1; m < 64; m <<= 1) ss += __shfl_xor(ss, m);
    float nrm = fmaxf(sqrtf(ss), 1e-12f);
    acc[(n << 6) + lane] = v * (sf[0] / nrm);
}

// ---- rank[k] = dot(acc[src[k]], acc[dst[k]]) ----
__global__ void k_rank(const float* __restrict__ acc, const int* __restrict__ eli,
                       float* __restrict__ rank) {
    int k    = (blockIdx.x << 2) + (threadIdx.x >> 6);
    int lane = threadIdx.x & 63;
    if (k >= LABELS) return;
    int s = eli[k];
    int d = eli[LABELS + k];
    float p = acc[(s << 6) + lane] * acc[(d << 6) + lane];
    #pragma unroll
    for (int m = 1; m < 64; m <<= 1) p += __shfl_xor(p, m);
    if (lane == 0) rank[k] = p;
}

// ---- out[which][i][j] = rank[which*4096+j] + beta[eli[LABELS+which*4096+i]] ----
__global__ void k_final(const float* __restrict__ rank, const float* __restrict__ beta,
                        const int* __restrict__ eli, float* __restrict__ out) {
    int t     = blockIdx.x * blockDim.x + threadIdx.x;   // [0, 2^23)
    int which = t >> 22;
    int tt    = t & ((1 << 22) - 1);
    int i     = tt >> 10;
    int j4    = (tt & 1023) << 2;
    int item  = eli[LABELS + (which << 12) + i];
    float b   = beta[item];
    const float* rk = rank + (which << 12);
    float4 r = *reinterpret_cast<const float4*>(rk + j4);
    float4 vv = make_float4(r.x + b, r.y + b, r.z + b, r.w + b);
    *reinterpret_cast<float4*>(out + ((size_t)t << 2)) = vv;
}

extern "C" void kernel_launch(void* const* d_in, const int* in_sizes, int n_in,
                              void* d_out, int out_size, void* d_ws, size_t ws_size,
                              hipStream_t stream) {
    const float* emb   = (const float*)d_in[0];
    const float* beta  = (const float*)d_in[1];
    const float* alpha = (const float*)d_in[2];
    const int*   eidx  = (const int*)d_in[3];
    const int*   eli   = (const int*)d_in[4];
    const float* sf    = (const float*)d_in[7];

    const int* row = eidx;
    const int* col = eidx + EDGES;

    // ---- workspace layout (4-byte units) ----
    char* ws = (char*)d_ws;
    int*      rowptr = (int*)     (ws);                   // NODES+1   [0 .. 151552)
    float*    dis    = (float*)   (ws + 151552u * 4);     // NODES
    int*      chist  = (int*)     (ws + 303104u * 4);     // NB (pad 1024)
    int*      cbase  = (int*)     (ws + 304128u * 4);     // NB+1 (pad 1024)
    int*      gcur   = (int*)     (ws + 305152u * 4);     // NB (pad 1024)
    float*    rank   = (float*)   (ws + 306176u * 4);     // LABELS
    unsigned* E      = (unsigned*)(ws + 315392u * 4);     // EDGES
    int*      src_s  = (int*)     (ws + 4315392u * 4);    // EDGES

    // layer ping-pong y buffers live in the unused tail of d_out (33.5M floats)
    float* acc = (float*)d_out;                           // NODES*DIM = 9.6M
    float* Y0  = (float*)d_out + 10485760;
    float* Y1  = (float*)d_out + 20971520;

    const int NV_BLK = (NODES * DIM + 255) / 256;
    const int NN4    = (NODES + 3) / 4;

    // ---- CSR build (two-level counting sort; emits rowptr + dis too) ----
    hipMemsetAsync(chist, 0, 1024 * sizeof(int), stream);
    k_chist<<<(EDGES + 4095) / 4096, 256, 0, stream>>>(col, chist);
    k_scanB<<<1, 64, 0, stream>>>(chist, cbase, gcur);
    k_cscatter<<<(EDGES + 8191) / 8192, 256, 0, stream>>>(row, col, gcur, E);
    k_fsort<<<NB, 256, 0, stream>>>(E, cbase, src_s, rowptr, dis);

    // ---- propagation (y-space) ----
    k_prep<<<NV_BLK, 256, 0, stream>>>(emb, alpha, dis, acc, Y0);
    k_gather<<<NN4, 256, 0, stream>>>(Y0, src_s, rowptr, dis, Y1, acc, alpha, 1, 1);
    k_gather<<<NN4, 256, 0, stream>>>(Y1, src_s, rowptr, dis, Y0, acc, alpha, 2, 1);
    k_gather<<<NN4, 256, 0, stream>>>(Y0, src_s, rowptr, dis, Y1, acc, alpha, 3, 0);

    // ---- epilogue ----
    k_norm_items<<<NITEMS / 4, 256, 0, stream>>>(acc, sf);
    k_rank<<<LABELS / 4, 256, 0, stream>>>(acc, eli, rank);
    k_final<<<(1 << 23) / 256, 256, 0, stream>>>(rank, beta, eli, (float*)d_out);
}

// Round 5
// 577.531 us; speedup vs baseline: 5.1220x; 1.1292x over previous
//
#include <hip/hip_runtime.h>
#include <hip/hip_bf16.h>
#include <cstdint>

#define NODES   150000
#define DIM     64
#define EDGES   4000000
#define LABELS  8192
#define NUSERS  100000
#define NITEMS  50000

#define NB      586          // ceil(NODES/256) coarse buckets of 256 nodes
#define CAP     10240        // LDS entry capacity per bucket (mean 6827, +41 sigma)

// ---- pass A: coarse histogram (LDS-privatized) ----
__global__ void k_chist(const int* __restrict__ col, int* __restrict__ chist) {
    __shared__ int h[NB];
    for (int i = threadIdx.x; i < NB; i += 256) h[i] = 0;
    __syncthreads();
    int base = blockIdx.x * 4096;
    #pragma unroll
    for (int k = 0; k < 16; ++k) {
        int e = base + k * 256 + threadIdx.x;
        if (e < EDGES) atomicAdd(&h[col[e] >> 8], 1);
    }
    __syncthreads();
    for (int i = threadIdx.x; i < NB; i += 256) if (h[i]) atomicAdd(&chist[i], h[i]);
}

// ---- scan of 586 bucket counts (one wave, shuffle scan) ----
__global__ void k_scanB(const int* __restrict__ chist, int* __restrict__ cbase,
                        int* __restrict__ gcur) {
    int lane = threadIdx.x;
    int run = 0;
    for (int base = 0; base < NB; base += 64) {
        int idx = base + lane;
        int v = (idx < NB) ? chist[idx] : 0;
        int inc = v;
        #pragma unroll
        for (int o = 1; o < 64; o <<= 1) {
            int t = __shfl_up(inc, o);
            if (lane >= o) inc += t;
        }
        int ex = run + inc - v;
        if (idx < NB) { cbase[idx] = ex; gcur[idx] = ex; }
        run += __shfl(inc, 63);
    }
    if (lane == 0) cbase[NB] = EDGES;
}

// ---- pass B: coarse scatter into bucket-partitioned packed array ----
__global__ void k_cscatter(const int* __restrict__ row, const int* __restrict__ col,
                           int* __restrict__ gcur, unsigned* __restrict__ E) {
    __shared__ int lhist[NB];
    __shared__ int lbase[NB];
    for (int i = threadIdx.x; i < NB; i += 256) lhist[i] = 0;
    __syncthreads();
    int base = blockIdx.x * 8192;
    #pragma unroll
    for (int k = 0; k < 32; ++k) {
        int e = base + k * 256 + threadIdx.x;
        if (e < EDGES) atomicAdd(&lhist[col[e] >> 8], 1);
    }
    __syncthreads();
    for (int i = threadIdx.x; i < NB; i += 256) {
        int c = lhist[i];
        lbase[i] = c ? atomicAdd(&gcur[i], c) : 0;
        lhist[i] = 0;                       // reuse as local cursor
    }
    __syncthreads();
    #pragma unroll
    for (int k = 0; k < 32; ++k) {
        int e = base + k * 256 + threadIdx.x;
        if (e < EDGES) {
            int c = col[e];
            int b = c >> 8;
            int r = atomicAdd(&lhist[b], 1);
            E[lbase[b] + r] = ((unsigned)(c & 255) << 18) | (unsigned)row[e];
        }
    }
}

// ---- pass C: fine sort within one bucket per block; emits rowptr + dis too ----
__global__ void k_fsort(const unsigned* __restrict__ E, const int* __restrict__ cbase,
                        int* __restrict__ src_s, int* __restrict__ rowptr,
                        float* __restrict__ dis) {
    __shared__ unsigned ebuf[CAP];
    __shared__ int hist[256];
    __shared__ int curs[256];
    int b = blockIdx.x;
    int base = cbase[b], end = cbase[b + 1];
    int cnt = end - base;
    int t = threadIdx.x;
    hist[t] = 0;
    __syncthreads();
    for (int i = t; i < cnt; i += 256) {
        unsigned p = E[base + i];
        if (i < CAP) ebuf[i] = p;
        atomicAdd(&hist[p >> 18], 1);
    }
    __syncthreads();
    int v = hist[t];
    int inc = v;
    #pragma unroll
    for (int o = 1; o < 256; o <<= 1) {
        int tmp = (t >= o) ? hist[t - o] : 0;
        __syncthreads();
        hist[t] = inc = inc + tmp;
        __syncthreads();
    }
    int ex = inc - v;
    curs[t] = ex;
    int node = (b << 8) + t;
    if (node < NODES) {
        rowptr[node] = base + ex;
        dis[node] = v > 0 ? rsqrtf((float)v) : 0.0f;
    }
    if (b == NB - 1 && t == 0) rowptr[NODES] = EDGES;
    __syncthreads();
    for (int i = t; i < cnt; i += 256) {
        unsigned p = (i < CAP) ? ebuf[i] : E[base + i];
        int c = p >> 18;
        int r = atomicAdd(&curs[c], 1);
        src_s[base + r] = (int)(p & 0x3FFFFu);
    }
}

// ---- y0 = bf16(dis ⊙ emb) ----
__global__ void k_prep(const float* __restrict__ emb, const float* __restrict__ dis,
                       __hip_bfloat16* __restrict__ y0) {
    int i = blockIdx.x * blockDim.x + threadIdx.x;
    if (i < NODES * DIM) y0[i] = __float2bfloat16(emb[i] * dis[i >> 6]);
}

// ---- one wave per destination node:  yn[n] = bf16(dis[n]^2 * sum y[src]) ----
__global__ void k_gather(const __hip_bfloat16* __restrict__ y, const int* __restrict__ src_s,
                         const int* __restrict__ rowptr, const float* __restrict__ dis,
                         __hip_bfloat16* __restrict__ yn) {
    int n    = (blockIdx.x << 2) + (threadIdx.x >> 6);
    int lane = threadIdx.x & 63;
    if (n >= NODES) return;
    int jb = rowptr[n], je = rowptr[n + 1];
    float a0 = 0.0f, a1 = 0.0f, a2 = 0.0f, a3 = 0.0f;
    int j = jb;
    for (; j + 3 < je; j += 4) {
        int s0 = src_s[j], s1 = src_s[j + 1], s2 = src_s[j + 2], s3 = src_s[j + 3];
        a0 += __bfloat162float(y[(s0 << 6) + lane]);
        a1 += __bfloat162float(y[(s1 << 6) + lane]);
        a2 += __bfloat162float(y[(s2 << 6) + lane]);
        a3 += __bfloat162float(y[(s3 << 6) + lane]);
    }
    for (; j < je; ++j) a0 += __bfloat162float(y[(src_s[j] << 6) + lane]);
    float s = (a0 + a1) + (a2 + a3);
    float d = dis[n];
    yn[(n << 6) + lane] = __float2bfloat16(d * d * s);
}

// ---- acc = a0*emb + sum a_i * (y_i / dis), fused item-row L2 normalize ----
__global__ void k_combine(const float* __restrict__ emb,
                          const __hip_bfloat16* __restrict__ y1,
                          const __hip_bfloat16* __restrict__ y2,
                          const __hip_bfloat16* __restrict__ y3,
                          const float* __restrict__ dis, const float* __restrict__ alpha,
                          const float* __restrict__ sf, float* __restrict__ acc) {
    int n    = (blockIdx.x << 2) + (threadIdx.x >> 6);
    int lane = threadIdx.x & 63;
    if (n >= NODES) return;
    int   o   = (n << 6) + lane;
    float d   = dis[n];
    float inv = d > 0.0f ? 1.0f / d : 0.0f;
    float v = alpha[0] * emb[o]
            + inv * (alpha[1] * __bfloat162float(y1[o])
                   + alpha[2] * __bfloat162float(y2[o])
                   + alpha[3] * __bfloat162float(y3[o]));
    if (n >= NUSERS) {
        float ss = v * v;
        #pragma unroll
        for (int m = 1; m < 64; m <<= 1) ss += __shfl_xor(ss, m);
        float nrm = fmaxf(sqrtf(ss), 1e-12f);
        v = v * (sf[0] / nrm);
    }
    acc[o] = v;
}

// ---- rank[k] = dot(acc[src[k]], acc[dst[k]]) ----
__global__ void k_rank(const float* __restrict__ acc, const int* __restrict__ eli,
                       float* __restrict__ rank) {
    int k    = (blockIdx.x << 2) + (threadIdx.x >> 6);
    int lane = threadIdx.x & 63;
    if (k >= LABELS) return;
    int s = eli[k];
    int d = eli[LABELS + k];
    float p = acc[(s << 6) + lane] * acc[(d << 6) + lane];
    #pragma unroll
    for (int m = 1; m < 64; m <<= 1) p += __shfl_xor(p, m);
    if (lane == 0) rank[k] = p;
}

// ---- out[which][i][j] = rank[which*4096+j] + beta[eli[LABELS+which*4096+i]] ----
__global__ void k_final(const float* __restrict__ rank, const float* __restrict__ beta,
                        const int* __restrict__ eli, float* __restrict__ out) {
    int t     = blockIdx.x * blockDim.x + threadIdx.x;   // [0, 2^23)
    int which = t >> 22;
    int tt    = t & ((1 << 22) - 1);
    int i     = tt >> 10;
    int j4    = (tt & 1023) << 2;
    int item  = eli[LABELS + (which << 12) + i];
    float b   = beta[item];
    const float* rk = rank + (which << 12);
    float4 r = *reinterpret_cast<const float4*>(rk + j4);
    float4 vv = make_float4(r.x + b, r.y + b, r.z + b, r.w + b);
    *reinterpret_cast<float4*>(out + ((size_t)t << 2)) = vv;
}

extern "C" void kernel_launch(void* const* d_in, const int* in_sizes, int n_in,
                              void* d_out, int out_size, void* d_ws, size_t ws_size,
                              hipStream_t stream) {
    const float* emb   = (const float*)d_in[0];
    const float* beta  = (const float*)d_in[1];
    const float* alpha = (const float*)d_in[2];
    const int*   eidx  = (const int*)d_in[3];
    const int*   eli   = (const int*)d_in[4];
    const float* sf    = (const float*)d_in[7];

    const int* row = eidx;
    const int* col = eidx + EDGES;

    // ---- workspace layout (4-byte units) ----
    char* ws = (char*)d_ws;
    int*      rowptr = (int*)     (ws);                   // NODES+1
    float*    dis    = (float*)   (ws + 151552u * 4);     // NODES
    int*      chist  = (int*)     (ws + 303104u * 4);     // NB (pad 1024)
    int*      cbase  = (int*)     (ws + 304128u * 4);     // NB+1 (pad 1024)
    int*      gcur   = (int*)     (ws + 305152u * 4);     // NB (pad 1024)
    float*    rank   = (float*)   (ws + 306176u * 4);     // LABELS
    unsigned* E      = (unsigned*)(ws + 315392u * 4);     // EDGES
    int*      src_s  = (int*)     (ws + 4315392u * 4);    // EDGES

    // acc (f32) in front of d_out; bf16 y ping-pong buffers in its tail
    float* acc = (float*)d_out;                           // 9.6M f32
    __hip_bfloat16* yb = (__hip_bfloat16*)((char*)d_out + 10485760u * 4);
    __hip_bfloat16* Y0 = yb;                              // 9.6M bf16 each, 10M spacing
    __hip_bfloat16* Y1 = yb + 10000000u;
    __hip_bfloat16* Y2 = yb + 20000000u;
    __hip_bfloat16* Y3 = yb + 30000000u;

    const int NV_BLK = (NODES * DIM + 255) / 256;
    const int NN4    = (NODES + 3) / 4;

    // ---- CSR build (two-level counting sort; emits rowptr + dis) ----
    hipMemsetAsync(chist, 0, 1024 * sizeof(int), stream);
    k_chist<<<(EDGES + 4095) / 4096, 256, 0, stream>>>(col, chist);
    k_scanB<<<1, 64, 0, stream>>>(chist, cbase, gcur);
    k_cscatter<<<(EDGES + 8191) / 8192, 256, 0, stream>>>(row, col, gcur, E);
    k_fsort<<<NB, 256, 0, stream>>>(E, cbase, src_s, rowptr, dis);

    // ---- propagation (bf16 y-space) ----
    k_prep<<<NV_BLK, 256, 0, stream>>>(emb, dis, Y0);
    k_gather<<<NN4, 256, 0, stream>>>(Y0, src_s, rowptr, dis, Y1);
    k_gather<<<NN4, 256, 0, stream>>>(Y1, src_s, rowptr, dis, Y2);
    k_gather<<<NN4, 256, 0, stream>>>(Y2, src_s, rowptr, dis, Y3);

    // ---- combine + epilogue ----
    k_combine<<<NN4, 256, 0, stream>>>(emb, Y1, Y2, Y3, dis, alpha, sf, acc);
    k_rank<<<LABELS / 4, 256, 0, stream>>>(acc, eli, rank);
    k_final<<<(1 << 23) / 256, 256, 0, stream>>>(rank, beta, eli, (float*)d_out);
}

// Round 6
// 449.184 us; speedup vs baseline: 6.5856x; 1.2857x over previous
//
#include <hip/hip_runtime.h>
#include <hip/hip_bf16.h>
#include <cstdint>

#define NODES   150000
#define DIM     64
#define EDGES   4000000
#define LABELS  8192
#define NUSERS  100000
#define NITEMS  50000

#define NB      586          // ceil(NODES/256) coarse buckets of 256 nodes
#define CAP     10240        // LDS entry capacity per bucket (mean 6827, +41 sigma)

// ---- pass A: coarse histogram (LDS-privatized) ----
__global__ void k_chist(const int* __restrict__ col, int* __restrict__ chist) {
    __shared__ int h[NB];
    for (int i = threadIdx.x; i < NB; i += 256) h[i] = 0;
    __syncthreads();
    int base = blockIdx.x * 4096;
    #pragma unroll
    for (int k = 0; k < 16; ++k) {
        int e = base + k * 256 + threadIdx.x;
        if (e < EDGES) atomicAdd(&h[col[e] >> 8], 1);
    }
    __syncthreads();
    for (int i = threadIdx.x; i < NB; i += 256) if (h[i]) atomicAdd(&chist[i], h[i]);
}

// ---- scan of 586 bucket counts (one wave, shuffle scan) ----
__global__ void k_scanB(const int* __restrict__ chist, int* __restrict__ cbase,
                        int* __restrict__ gcur) {
    int lane = threadIdx.x;
    int run = 0;
    for (int base = 0; base < NB; base += 64) {
        int idx = base + lane;
        int v = (idx < NB) ? chist[idx] : 0;
        int inc = v;
        #pragma unroll
        for (int o = 1; o < 64; o <<= 1) {
            int t = __shfl_up(inc, o);
            if (lane >= o) inc += t;
        }
        int ex = run + inc - v;
        if (idx < NB) { cbase[idx] = ex; gcur[idx] = ex; }
        run += __shfl(inc, 63);
    }
    if (lane == 0) cbase[NB] = EDGES;
}

// ---- pass B: coarse scatter into bucket-partitioned packed array ----
__global__ void k_cscatter(const int* __restrict__ row, const int* __restrict__ col,
                           int* __restrict__ gcur, unsigned* __restrict__ E) {
    __shared__ int lhist[NB];
    __shared__ int lbase[NB];
    for (int i = threadIdx.x; i < NB; i += 256) lhist[i] = 0;
    __syncthreads();
    int base = blockIdx.x * 8192;
    #pragma unroll
    for (int k = 0; k < 32; ++k) {
        int e = base + k * 256 + threadIdx.x;
        if (e < EDGES) atomicAdd(&lhist[col[e] >> 8], 1);
    }
    __syncthreads();
    for (int i = threadIdx.x; i < NB; i += 256) {
        int c = lhist[i];
        lbase[i] = c ? atomicAdd(&gcur[i], c) : 0;
        lhist[i] = 0;                       // reuse as local cursor
    }
    __syncthreads();
    #pragma unroll
    for (int k = 0; k < 32; ++k) {
        int e = base + k * 256 + threadIdx.x;
        if (e < EDGES) {
            int c = col[e];
            int b = c >> 8;
            int r = atomicAdd(&lhist[b], 1);
            E[lbase[b] + r] = ((unsigned)(c & 255) << 18) | (unsigned)row[e];
        }
    }
}

// ---- pass C: fine sort within one bucket per block; emits rowptr + dis too ----
__global__ void k_fsort(const unsigned* __restrict__ E, const int* __restrict__ cbase,
                        int* __restrict__ src_s, int* __restrict__ rowptr,
                        float* __restrict__ dis) {
    __shared__ unsigned ebuf[CAP];
    __shared__ int hist[256];
    __shared__ int curs[256];
    int b = blockIdx.x;
    int base = cbase[b], end = cbase[b + 1];
    int cnt = end - base;
    int t = threadIdx.x;
    hist[t] = 0;
    __syncthreads();
    for (int i = t; i < cnt; i += 256) {
        unsigned p = E[base + i];
        if (i < CAP) ebuf[i] = p;
        atomicAdd(&hist[p >> 18], 1);
    }
    __syncthreads();
    int v = hist[t];
    int inc = v;
    #pragma unroll
    for (int o = 1; o < 256; o <<= 1) {
        int tmp = (t >= o) ? hist[t - o] : 0;
        __syncthreads();
        hist[t] = inc = inc + tmp;
        __syncthreads();
    }
    int ex = inc - v;
    curs[t] = ex;
    int node = (b << 8) + t;
    if (node < NODES) {
        rowptr[node] = base + ex;
        dis[node] = v > 0 ? rsqrtf((float)v) : 0.0f;
    }
    if (b == NB - 1 && t == 0) rowptr[NODES] = EDGES;
    __syncthreads();
    for (int i = t; i < cnt; i += 256) {
        unsigned p = (i < CAP) ? ebuf[i] : E[base + i];
        int c = p >> 18;
        int r = atomicAdd(&curs[c], 1);
        src_s[base + r] = (int)(p & 0x3FFFFu);
    }
}

// ---- y0 = bf16(dis ⊙ emb) ----
__global__ void k_prep(const float* __restrict__ emb, const float* __restrict__ dis,
                       __hip_bfloat16* __restrict__ y0) {
    int i = blockIdx.x * blockDim.x + threadIdx.x;
    if (i < NODES * DIM) y0[i] = __float2bfloat16(emb[i] * dis[i >> 6]);
}

// Edge-sum core: coalesced index preload + shuffle broadcast + 8-deep MLP.
// Returns sum over the node's edge list of y[src][lane].
__device__ __forceinline__ float edge_sum(const __hip_bfloat16* __restrict__ y,
                                          const int* __restrict__ src_s,
                                          int jb, int deg, int lane) {
    float a0 = 0.f, a1 = 0.f, a2 = 0.f, a3 = 0.f,
          a4 = 0.f, a5 = 0.f, a6 = 0.f, a7 = 0.f;
    for (int base = 0; base < deg; base += 64) {
        int rem = deg - base;
        int m   = rem < 64 ? rem : 64;
        int idx = (base + lane < deg) ? src_s[jb + base + lane] : 0;
        int j = 0;
        for (; j + 8 <= m; j += 8) {
            int s0 = __shfl(idx, j + 0), s1 = __shfl(idx, j + 1);
            int s2 = __shfl(idx, j + 2), s3 = __shfl(idx, j + 3);
            int s4 = __shfl(idx, j + 4), s5 = __shfl(idx, j + 5);
            int s6 = __shfl(idx, j + 6), s7 = __shfl(idx, j + 7);
            a0 += __bfloat162float(y[(s0 << 6) + lane]);
            a1 += __bfloat162float(y[(s1 << 6) + lane]);
            a2 += __bfloat162float(y[(s2 << 6) + lane]);
            a3 += __bfloat162float(y[(s3 << 6) + lane]);
            a4 += __bfloat162float(y[(s4 << 6) + lane]);
            a5 += __bfloat162float(y[(s5 << 6) + lane]);
            a6 += __bfloat162float(y[(s6 << 6) + lane]);
            a7 += __bfloat162float(y[(s7 << 6) + lane]);
        }
        for (; j < m; ++j) {
            int s = __shfl(idx, j);
            a0 += __bfloat162float(y[(s << 6) + lane]);
        }
    }
    return ((a0 + a1) + (a2 + a3)) + ((a4 + a5) + (a6 + a7));
}

// ---- layers 1,2:  yn[n] = bf16(dis[n]^2 * sum y[src]) ----
__global__ void k_gather(const __hip_bfloat16* __restrict__ y, const int* __restrict__ src_s,
                         const int* __restrict__ rowptr, const float* __restrict__ dis,
                         __hip_bfloat16* __restrict__ yn) {
    int n    = (blockIdx.x << 2) + (threadIdx.x >> 6);
    int lane = threadIdx.x & 63;
    if (n >= NODES) return;
    int jb = rowptr[n];
    int deg = rowptr[n + 1] - jb;
    float s = edge_sum(y, src_s, jb, deg, lane);
    float d = dis[n];
    yn[(n << 6) + lane] = __float2bfloat16(d * d * s);
}

// ---- layer 3 fused with combine + item L2-normalize ----
// x3 = dis[n] * sum y2[src];  acc = a0*emb + (a1*y1 + a2*y2)/dis + a3*x3
__global__ void k_gather3(const __hip_bfloat16* __restrict__ y2,
                          const __hip_bfloat16* __restrict__ y1,
                          const float* __restrict__ emb, const int* __restrict__ src_s,
                          const int* __restrict__ rowptr, const float* __restrict__ dis,
                          const float* __restrict__ alpha, const float* __restrict__ sf,
                          float* __restrict__ acc) {
    int n    = (blockIdx.x << 2) + (threadIdx.x >> 6);
    int lane = threadIdx.x & 63;
    if (n >= NODES) return;
    int jb = rowptr[n];
    int deg = rowptr[n + 1] - jb;
    float s = edge_sum(y2, src_s, jb, deg, lane);
    float d   = dis[n];
    float inv = d > 0.0f ? 1.0f / d : 0.0f;
    int   o   = (n << 6) + lane;
    float v = alpha[0] * emb[o]
            + inv * (alpha[1] * __bfloat162float(y1[o])
                   + alpha[2] * __bfloat162float(y2[o]))
            + alpha[3] * d * s;
    if (n >= NUSERS) {
        float ss = v * v;
        #pragma unroll
        for (int m = 1; m < 64; m <<= 1) ss += __shfl_xor(ss, m);
        float nrm = fmaxf(sqrtf(ss), 1e-12f);
        v = v * (sf[0] / nrm);
    }
    acc[o] = v;
}

// ---- rank[k] = dot(acc[src[k]], acc[dst[k]]) ----
__global__ void k_rank(const float* __restrict__ acc, const int* __restrict__ eli,
                       float* __restrict__ rank) {
    int k    = (blockIdx.x << 2) + (threadIdx.x >> 6);
    int lane = threadIdx.x & 63;
    if (k >= LABELS) return;
    int s = eli[k];
    int d = eli[LABELS + k];
    float p = acc[(s << 6) + lane] * acc[(d << 6) + lane];
    #pragma unroll
    for (int m = 1; m < 64; m <<= 1) p += __shfl_xor(p, m);
    if (lane == 0) rank[k] = p;
}

// ---- out[which][i][j] = rank[which*4096+j] + beta[eli[LABELS+which*4096+i]] ----
__global__ void k_final(const float* __restrict__ rank, const float* __restrict__ beta,
                        const int* __restrict__ eli, float* __restrict__ out) {
    int t     = blockIdx.x * blockDim.x + threadIdx.x;   // [0, 2^23)
    int which = t >> 22;
    int tt    = t & ((1 << 22) - 1);
    int i     = tt >> 10;
    int j4    = (tt & 1023) << 2;
    int item  = eli[LABELS + (which << 12) + i];
    float b   = beta[item];
    const float* rk = rank + (which << 12);
    float4 r = *reinterpret_cast<const float4*>(rk + j4);
    float4 vv = make_float4(r.x + b, r.y + b, r.z + b, r.w + b);
    *reinterpret_cast<float4*>(out + ((size_t)t << 2)) = vv;
}

extern "C" void kernel_launch(void* const* d_in, const int* in_sizes, int n_in,
                              void* d_out, int out_size, void* d_ws, size_t ws_size,
                              hipStream_t stream) {
    const float* emb   = (const float*)d_in[0];
    const float* beta  = (const float*)d_in[1];
    const float* alpha = (const float*)d_in[2];
    const int*   eidx  = (const int*)d_in[3];
    const int*   eli   = (const int*)d_in[4];
    const float* sf    = (const float*)d_in[7];

    const int* row = eidx;
    const int* col = eidx + EDGES;

    // ---- workspace layout (4-byte units) ----
    char* ws = (char*)d_ws;
    int*      rowptr = (int*)     (ws);                   // NODES+1
    float*    dis    = (float*)   (ws + 151552u * 4);     // NODES
    int*      chist  = (int*)     (ws + 303104u * 4);     // NB (pad 1024)
    int*      cbase  = (int*)     (ws + 304128u * 4);     // NB+1 (pad 1024)
    int*      gcur   = (int*)     (ws + 305152u * 4);     // NB (pad 1024)
    float*    rank   = (float*)   (ws + 306176u * 4);     // LABELS
    unsigned* E      = (unsigned*)(ws + 315392u * 4);     // EDGES
    int*      src_s  = (int*)     (ws + 4315392u * 4);    // EDGES

    // acc (f32) in front of d_out; bf16 y buffers in its tail
    float* acc = (float*)d_out;                           // 9.6M f32
    __hip_bfloat16* yb = (__hip_bfloat16*)((char*)d_out + 10485760u * 4);
    __hip_bfloat16* Y0 = yb;                              // 9.6M bf16 each, 10M spacing
    __hip_bfloat16* Y1 = yb + 10000000u;
    __hip_bfloat16* Y2 = yb + 20000000u;

    const int NV_BLK = (NODES * DIM + 255) / 256;
    const int NN4    = (NODES + 3) / 4;

    // ---- CSR build (two-level counting sort; emits rowptr + dis) ----
    hipMemsetAsync(chist, 0, 1024 * sizeof(int), stream);
    k_chist<<<(EDGES + 4095) / 4096, 256, 0, stream>>>(col, chist);
    k_scanB<<<1, 64, 0, stream>>>(chist, cbase, gcur);
    k_cscatter<<<(EDGES + 8191) / 8192, 256, 0, stream>>>(row, col, gcur, E);
    k_fsort<<<NB, 256, 0, stream>>>(E, cbase, src_s, rowptr, dis);

    // ---- propagation (bf16 y-space) ----
    k_prep<<<NV_BLK, 256, 0, stream>>>(emb, dis, Y0);
    k_gather<<<NN4, 256, 0, stream>>>(Y0, src_s, rowptr, dis, Y1);
    k_gather<<<NN4, 256, 0, stream>>>(Y1, src_s, rowptr, dis, Y2);
    k_gather3<<<NN4, 256, 0, stream>>>(Y2, Y1, emb, src_s, rowptr, dis, alpha, sf, acc);

    // ---- epilogue ----
    k_rank<<<LABELS / 4, 256, 0, stream>>>(acc, eli, rank);
    k_final<<<(1 << 23) / 256, 256, 0, stream>>>(rank, beta, eli, (float*)d_out);
}

// Round 8
// 407.656 us; speedup vs baseline: 7.2564x; 1.1019x over previous
//
#include <hip/hip_runtime.h>
#include <hip/hip_bf16.h>
#include <cstdint>

#define NODES   150000
#define DIM     64
#define EDGES   4000000
#define LABELS  8192
#define NUSERS  100000
#define NITEMS  50000

#define NB      586          // ceil(NODES/256) coarse buckets of 256 nodes
#define CAP     10240        // LDS entry capacity per bucket (mean 6827, +41 sigma)

// ---- pass A: coarse histogram (LDS-privatized) ----
__global__ void k_chist(const int* __restrict__ col, int* __restrict__ chist) {
    __shared__ int h[NB];
    for (int i = threadIdx.x; i < NB; i += 256) h[i] = 0;
    __syncthreads();
    int base = blockIdx.x * 4096;
    #pragma unroll
    for (int k = 0; k < 16; ++k) {
        int e = base + k * 256 + threadIdx.x;
        if (e < EDGES) atomicAdd(&h[col[e] >> 8], 1);
    }
    __syncthreads();
    for (int i = threadIdx.x; i < NB; i += 256) if (h[i]) atomicAdd(&chist[i], h[i]);
}

// ---- scan of 586 bucket counts (one wave, shuffle scan) ----
__global__ void k_scanB(const int* __restrict__ chist, int* __restrict__ cbase,
                        int* __restrict__ gcur) {
    int lane = threadIdx.x;
    int run = 0;
    for (int base = 0; base < NB; base += 64) {
        int idx = base + lane;
        int v = (idx < NB) ? chist[idx] : 0;
        int inc = v;
        #pragma unroll
        for (int o = 1; o < 64; o <<= 1) {
            int t = __shfl_up(inc, o);
            if (lane >= o) inc += t;
        }
        int ex = run + inc - v;
        if (idx < NB) { cbase[idx] = ex; gcur[idx] = ex; }
        run += __shfl(inc, 63);
    }
    if (lane == 0) cbase[NB] = EDGES;
}

// ---- pass B: coarse scatter into bucket-partitioned packed array ----
__global__ void k_cscatter(const int* __restrict__ row, const int* __restrict__ col,
                           int* __restrict__ gcur, unsigned* __restrict__ E) {
    __shared__ int lhist[NB];
    __shared__ int lbase[NB];
    for (int i = threadIdx.x; i < NB; i += 256) lhist[i] = 0;
    __syncthreads();
    int base = blockIdx.x * 8192;
    #pragma unroll
    for (int k = 0; k < 32; ++k) {
        int e = base + k * 256 + threadIdx.x;
        if (e < EDGES) atomicAdd(&lhist[col[e] >> 8], 1);
    }
    __syncthreads();
    for (int i = threadIdx.x; i < NB; i += 256) {
        int c = lhist[i];
        lbase[i] = c ? atomicAdd(&gcur[i], c) : 0;
        lhist[i] = 0;                       // reuse as local cursor
    }
    __syncthreads();
    #pragma unroll
    for (int k = 0; k < 32; ++k) {
        int e = base + k * 256 + threadIdx.x;
        if (e < EDGES) {
            int c = col[e];
            int b = c >> 8;
            int r = atomicAdd(&lhist[b], 1);
            E[lbase[b] + r] = ((unsigned)(c & 255) << 18) | (unsigned)row[e];
        }
    }
}

// ---- pass C: fine sort within one bucket per block; emits rowptr + dis too ----
__global__ void k_fsort(const unsigned* __restrict__ E, const int* __restrict__ cbase,
                        int* __restrict__ src_s, int* __restrict__ rowptr,
                        float* __restrict__ dis) {
    __shared__ unsigned ebuf[CAP];
    __shared__ int hist[256];
    __shared__ int curs[256];
    int b = blockIdx.x;
    int base = cbase[b], end = cbase[b + 1];
    int cnt = end - base;
    int t = threadIdx.x;
    hist[t] = 0;
    __syncthreads();
    for (int i = t; i < cnt; i += 256) {
        unsigned p = E[base + i];
        if (i < CAP) ebuf[i] = p;
        atomicAdd(&hist[p >> 18], 1);
    }
    __syncthreads();
    int v = hist[t];
    int inc = v;
    #pragma unroll
    for (int o = 1; o < 256; o <<= 1) {
        int tmp = (t >= o) ? hist[t - o] : 0;
        __syncthreads();
        hist[t] = inc = inc + tmp;
        __syncthreads();
    }
    int ex = inc - v;
    curs[t] = ex;
    int node = (b << 8) + t;
    if (node < NODES) {
        rowptr[node] = base + ex;
        dis[node] = v > 0 ? rsqrtf((float)v) : 0.0f;
    }
    if (b == NB - 1 && t == 0) rowptr[NODES] = EDGES;
    __syncthreads();
    for (int i = t; i < cnt; i += 256) {
        unsigned p = (i < CAP) ? ebuf[i] : E[base + i];
        int c = p >> 18;
        int r = atomicAdd(&curs[c], 1);
        src_s[base + r] = (int)(p & 0x3FFFFu);
    }
}

// ---- y0 = bf16(dis ⊙ emb) ----
__global__ void k_prep(const float* __restrict__ emb, const float* __restrict__ dis,
                       __hip_bfloat16* __restrict__ y0) {
    int i = blockIdx.x * blockDim.x + threadIdx.x;
    if (i < NODES * DIM) y0[i] = __float2bfloat16(emb[i] * dis[i >> 6]);
}

__device__ __forceinline__ float bflo(unsigned d) {
    unsigned u = d << 16;
    return __uint_as_float(u);
}
__device__ __forceinline__ float bfhi(unsigned d) {
    unsigned u = d & 0xffff0000u;
    return __uint_as_float(u);
}

// Edge-sum core, half-wave paired: lanes 0-31 = even edges, 32-63 = odd edges.
// yd = y as dwords (bf16x2); lane q=l&31 owns dims {2q,2q+1}.
// Returns float2 partial sum; caller must shfl_xor(32)-combine.
// NOTE: every __shfl here executes with ALL 64 lanes active (uniform
// conditions only) — divergent shfl from an inactive source lane is
// undefined on CDNA (ds_bpermute), which was R7's bug.
__device__ __forceinline__ float2 edge_sum2(const unsigned* __restrict__ yd,
                                            const int* __restrict__ src_s,
                                            int jb, int deg, int lane) {
    int h = lane >> 5;
    int q = lane & 31;
    float ax0 = 0.f, ay0 = 0.f, ax1 = 0.f, ay1 = 0.f,
          ax2 = 0.f, ay2 = 0.f, ax3 = 0.f, ay3 = 0.f;
    for (int base = 0; base < deg; base += 64) {
        int rem = deg - base;
        int m   = rem < 64 ? rem : 64;
        int idx = (base + lane < deg) ? src_s[jb + base + lane] : 0;
        int j = 0;
        for (; j + 8 <= m; j += 8) {
            int s0 = __shfl(idx, j + 0 + h);
            int s1 = __shfl(idx, j + 2 + h);
            int s2 = __shfl(idx, j + 4 + h);
            int s3 = __shfl(idx, j + 6 + h);
            unsigned d0 = yd[(s0 << 5) + q];
            unsigned d1 = yd[(s1 << 5) + q];
            unsigned d2 = yd[(s2 << 5) + q];
            unsigned d3 = yd[(s3 << 5) + q];
            ax0 += bflo(d0); ay0 += bfhi(d0);
            ax1 += bflo(d1); ay1 += bfhi(d1);
            ax2 += bflo(d2); ay2 += bfhi(d2);
            ax3 += bflo(d3); ay3 += bfhi(d3);
        }
        for (; j + 2 <= m; j += 2) {
            int s = __shfl(idx, j + h);
            unsigned d = yd[(s << 5) + q];
            ax0 += bflo(d); ay0 += bfhi(d);
        }
        if (j < m) {                          // odd leftover
            int s = __shfl(idx, j);           // uniform: all 64 lanes shuffle
            if (h == 0) {                     // only half 0 accumulates
                unsigned d = yd[(s << 5) + q];
                ax0 += bflo(d); ay0 += bfhi(d);
            }
        }
    }
    float2 r;
    r.x = (ax0 + ax1) + (ax2 + ax3);
    r.y = (ay0 + ay1) + (ay2 + ay3);
    return r;
}

// ---- layers 1,2:  yn[n] = bf16(dis[n]^2 * sum y[src]) ----
__global__ void k_gather(const __hip_bfloat16* __restrict__ y, const int* __restrict__ src_s,
                         const int* __restrict__ rowptr, const float* __restrict__ dis,
                         __hip_bfloat16* __restrict__ yn) {
    int n    = (blockIdx.x << 2) + (threadIdx.x >> 6);
    int lane = threadIdx.x & 63;
    if (n >= NODES) return;
    int jb  = rowptr[n];
    int deg = rowptr[n + 1] - jb;
    float2 a = edge_sum2((const unsigned*)y, src_s, jb, deg, lane);
    a.x += __shfl_xor(a.x, 32);
    a.y += __shfl_xor(a.y, 32);
    float dd = dis[n]; dd = dd * dd;
    if (lane < 32) {
        __hip_bfloat16 lo = __float2bfloat16(dd * a.x);
        __hip_bfloat16 hi = __float2bfloat16(dd * a.y);
        unsigned pk = ((unsigned)*(unsigned short*)&hi << 16) | *(unsigned short*)&lo;
        ((unsigned*)yn)[(n << 5) + lane] = pk;
    }
}

// ---- layer 3 fused with combine + item L2-normalize ----
__global__ void k_gather3(const __hip_bfloat16* __restrict__ y2,
                          const __hip_bfloat16* __restrict__ y1,
                          const float* __restrict__ emb, const int* __restrict__ src_s,
                          const int* __restrict__ rowptr, const float* __restrict__ dis,
                          const float* __restrict__ alpha, const float* __restrict__ sf,
                          float* __restrict__ acc) {
    int n    = (blockIdx.x << 2) + (threadIdx.x >> 6);
    int lane = threadIdx.x & 63;
    if (n >= NODES) return;
    int q  = lane & 31;
    int jb = rowptr[n];
    int deg = rowptr[n + 1] - jb;
    float2 a = edge_sum2((const unsigned*)y2, src_s, jb, deg, lane);
    a.x += __shfl_xor(a.x, 32);
    a.y += __shfl_xor(a.y, 32);
    float d   = dis[n];
    float inv = d > 0.0f ? 1.0f / d : 0.0f;
    int   o32 = (n << 5) + q;
    float2 e2 = ((const float2*)emb)[o32];
    unsigned y1d = ((const unsigned*)y1)[o32];
    unsigned y2d = ((const unsigned*)y2)[o32];
    float a0 = alpha[0], a1 = alpha[1], a2 = alpha[2], a3 = alpha[3];
    float2 v;
    v.x = a0 * e2.x + inv * (a1 * bflo(y1d) + a2 * bflo(y2d)) + a3 * d * a.x;
    v.y = a0 * e2.y + inv * (a1 * bfhi(y1d) + a2 * bfhi(y2d)) + a3 * d * a.y;
    if (n >= NUSERS) {
        float ss = v.x * v.x + v.y * v.y;
        #pragma unroll
        for (int m = 1; m < 32; m <<= 1) ss += __shfl_xor(ss, m);
        float nrm = fmaxf(sqrtf(ss), 1e-12f);
        float sc  = sf[0] / nrm;
        v.x *= sc; v.y *= sc;
    }
    if (lane < 32) ((float2*)acc)[o32] = v;
}

// ---- rank[k] = dot(acc[src[k]], acc[dst[k]]) : 32 lanes per pair, float2 ----
__global__ void k_rank(const float* __restrict__ acc, const int* __restrict__ eli,
                       float* __restrict__ rank) {
    int k    = (blockIdx.x << 3) + (threadIdx.x >> 5);
    int q    = threadIdx.x & 31;
    if (k >= LABELS) return;
    int s = eli[k];
    int d = eli[LABELS + k];
    float2 vs = ((const float2*)acc)[(s << 5) + q];
    float2 vd = ((const float2*)acc)[(d << 5) + q];
    float p = vs.x * vd.x + vs.y * vd.y;
    #pragma unroll
    for (int m = 1; m < 32; m <<= 1) p += __shfl_xor(p, m);
    if (q == 0) rank[k] = p;
}

// ---- out[which][i][j] = rank[which*4096+j] + beta[eli[LABELS+which*4096+i]] ----
__global__ void k_final(const float* __restrict__ rank, const float* __restrict__ beta,
                        const int* __restrict__ eli, float* __restrict__ out) {
    int t     = blockIdx.x * blockDim.x + threadIdx.x;   // [0, 2^23)
    int which = t >> 22;
    int tt    = t & ((1 << 22) - 1);
    int i     = tt >> 10;
    int j4    = (tt & 1023) << 2;
    int item  = eli[LABELS + (which << 12) + i];
    float b   = beta[item];
    const float* rk = rank + (which << 12);
    float4 r = *reinterpret_cast<const float4*>(rk + j4);
    float4 vv = make_float4(r.x + b, r.y + b, r.z + b, r.w + b);
    *reinterpret_cast<float4*>(out + ((size_t)t << 2)) = vv;
}

extern "C" void kernel_launch(void* const* d_in, const int* in_sizes, int n_in,
                              void* d_out, int out_size, void* d_ws, size_t ws_size,
                              hipStream_t stream) {
    const float* emb   = (const float*)d_in[0];
    const float* beta  = (const float*)d_in[1];
    const float* alpha = (const float*)d_in[2];
    const int*   eidx  = (const int*)d_in[3];
    const int*   eli   = (const int*)d_in[4];
    const float* sf    = (const float*)d_in[7];

    const int* row = eidx;
    const int* col = eidx + EDGES;

    // ---- workspace layout (4-byte units) ----
    char* ws = (char*)d_ws;
    int*      rowptr = (int*)     (ws);                   // NODES+1
    float*    dis    = (float*)   (ws + 151552u * 4);     // NODES
    int*      chist  = (int*)     (ws + 303104u * 4);     // NB (pad 1024)
    int*      cbase  = (int*)     (ws + 304128u * 4);     // NB+1 (pad 1024)
    int*      gcur   = (int*)     (ws + 305152u * 4);     // NB (pad 1024)
    float*    rank   = (float*)   (ws + 306176u * 4);     // LABELS
    unsigned* E      = (unsigned*)(ws + 315392u * 4);     // EDGES
    int*      src_s  = (int*)     (ws + 4315392u * 4);    // EDGES

    // acc (f32) in front of d_out; bf16 y buffers in its tail
    float* acc = (float*)d_out;                           // 9.6M f32
    __hip_bfloat16* yb = (__hip_bfloat16*)((char*)d_out + 10485760u * 4);
    __hip_bfloat16* Y0 = yb;                              // 9.6M bf16 each, 10M spacing
    __hip_bfloat16* Y1 = yb + 10000000u;
    __hip_bfloat16* Y2 = yb + 20000000u;

    const int NV_BLK = (NODES * DIM + 255) / 256;
    const int NN4    = (NODES + 3) / 4;

    // ---- CSR build (two-level counting sort; emits rowptr + dis) ----
    hipMemsetAsync(chist, 0, 1024 * sizeof(int), stream);
    k_chist<<<(EDGES + 4095) / 4096, 256, 0, stream>>>(col, chist);
    k_scanB<<<1, 64, 0, stream>>>(chist, cbase, gcur);
    k_cscatter<<<(EDGES + 8191) / 8192, 256, 0, stream>>>(row, col, gcur, E);
    k_fsort<<<NB, 256, 0, stream>>>(E, cbase, src_s, rowptr, dis);

    // ---- propagation (bf16 y-space) ----
    k_prep<<<NV_BLK, 256, 0, stream>>>(emb, dis, Y0);
    k_gather<<<NN4, 256, 0, stream>>>(Y0, src_s, rowptr, dis, Y1);
    k_gather<<<NN4, 256, 0, stream>>>(Y1, src_s, rowptr, dis, Y2);
    k_gather3<<<NN4, 256, 0, stream>>>(Y2, Y1, emb, src_s, rowptr, dis, alpha, sf, acc);

    // ---- epilogue ----
    k_rank<<<LABELS / 8, 256, 0, stream>>>(acc, eli, rank);
    k_final<<<(1 << 23) / 256, 256, 0, stream>>>(rank, beta, eli, (float*)d_out);
}